// Round 7
// baseline (1652.518 us; speedup 1.0000x reference)
//
#include <hip/hip_runtime.h>
#include <cstddef>
#include <cstdint>

// ---------------------------------------------------------------------------
// N=50000 nodes, E=1,650,000 edges (incl. self loops). Stages (in,out):
// (512,384),(384,256),(256,128), FC 128->128.
// Pipeline (all activations/weights fp16, accumulation fp32):
//   convert -> [per stage: MFMA GEMM (panel-major out) -> panel-XCD agg] -> FC
// GEMM-first restructuring: (A h) W^T == A (h W^T); row scales commute.
// R7: agg gather made per-XCD L2-resident WITHOUT extra launches/sync:
//     panel = blockIdx.x & 7 rides the HW round-robin block->XCD mapping, so
//     each XCD's L2 holds exactly one N x W column panel (4.8/3.2/3.2 MB).
//     Z written panel-major by the GEMM epilogue; csr/out use nontemporal
//     hints to keep streams from evicting the panel. Output bitwise-identical
//     (per-column edge order unchanged). R2's panel attempt failed on 48-
//     launch overhead, not the mechanism; this is 1 launch per agg.
// ---------------------------------------------------------------------------

typedef _Float16 h8 __attribute__((ext_vector_type(8)));
typedef _Float16 h4 __attribute__((ext_vector_type(4)));
typedef float f32x4 __attribute__((ext_vector_type(4)));

#define HB 64    // src-histogram blocks
#define NCH 256  // dst chunks (per-chunk count <= E/256 = 6446 < 65536)

// ---------------- degree / CSR build (no global atomics) ----------------

__global__ __launch_bounds__(1024) void histo_dst_kernel(
    const int* __restrict__ dst, uint32_t* __restrict__ H,
    int* __restrict__ ord, int E, int bins2, int CE) {
  __shared__ uint32_t hh[25088];  // 100 KB, 2 x u16 bins per u32
  for (int i = threadIdx.x; i < bins2; i += 1024) hh[i] = 0;
  __syncthreads();
  const int base = blockIdx.x * CE;
  int lim = base + CE; if (lim > E) lim = E;
  for (int e = base + (int)threadIdx.x; e < lim; e += 1024) {
    int d = dst[e];
    const int sh = (d & 1) * 16;
    uint32_t old = atomicAdd(&hh[d >> 1], 1u << sh);
    ord[e] = (int)((old >> sh) & 0xFFFFu);
  }
  __syncthreads();
  uint32_t* out = H + (size_t)blockIdx.x * bins2;
  for (int i = threadIdx.x; i < bins2; i += 1024) out[i] = hh[i];
}

__global__ __launch_bounds__(1024) void histo_out_kernel(
    const int* __restrict__ src, uint32_t* __restrict__ H, int E, int bins2) {
  __shared__ uint32_t hh[25088];
  for (int i = threadIdx.x; i < bins2; i += 1024) hh[i] = 0;
  __syncthreads();
  const int C = (E + HB - 1) / HB;
  const int base = blockIdx.x * C;
  int lim = base + C; if (lim > E) lim = E;
  for (int e = base + (int)threadIdx.x; e < lim; e += 1024) {
    int s = src[e];
    atomicAdd(&hh[s >> 1], 1u << ((s & 1) * 16));
  }
  __syncthreads();
  uint32_t* out = H + (size_t)blockIdx.x * bins2;
  for (int i = threadIdx.x; i < bins2; i += 1024) out[i] = hh[i];
}

// exclusive scan of Hdst along chunks (packed u16) -> bases + in-degree;
// fused sum of Hsrc -> out-degree.
__global__ __launch_bounds__(256) void chunk_scan_kernel(
    uint32_t* __restrict__ Hd, const uint32_t* __restrict__ Hs,
    int* __restrict__ in_deg, int* __restrict__ out_deg, int bins2, int n) {
  int i = blockIdx.x * 256 + threadIdx.x;
  if (i >= bins2) return;
  uint32_t lo = 0, hi = 0;
  for (int c = 0; c < NCH; ++c) {
    uint32_t* p = Hd + (size_t)c * bins2 + i;
    uint32_t v = *p;
    *p = lo | (hi << 16);
    lo += v & 0xFFFFu;
    hi += v >> 16;
  }
  in_deg[2 * i] = (int)lo;
  if (2 * i + 1 < n) in_deg[2 * i + 1] = (int)hi;
  uint32_t slo = 0, shi = 0;
  for (int b = 0; b < HB; ++b) {
    uint32_t v = Hs[(size_t)b * bins2 + i];
    slo += v & 0xFFFFu;
    shi += v >> 16;
  }
  out_deg[2 * i] = (int)slo;
  if (2 * i + 1 < n) out_deg[2 * i + 1] = (int)shi;
}

// ---- 3-phase scan of in_deg -> row_ptr (nb <= 256 blocks of 256) ----

__global__ __launch_bounds__(256) void scan_a(
    const int* __restrict__ deg, int* __restrict__ bsum, int n) {
  __shared__ int s[256];
  int i = blockIdx.x * 256 + threadIdx.x;
  s[threadIdx.x] = (i < n) ? deg[i] : 0;
  __syncthreads();
  #pragma unroll
  for (int off = 128; off > 0; off >>= 1) {
    if ((int)threadIdx.x < off) s[threadIdx.x] += s[threadIdx.x + off];
    __syncthreads();
  }
  if (threadIdx.x == 0) bsum[blockIdx.x] = s[0];
}

__global__ __launch_bounds__(256) void scan_b(
    int* __restrict__ bsum, int* __restrict__ rp, int nb, int n) {
  __shared__ int s[256];
  const int t = threadIdx.x;
  int v = (t < nb) ? bsum[t] : 0;
  s[t] = v;
  __syncthreads();
  #pragma unroll
  for (int off = 1; off < 256; off <<= 1) {
    int a = (t >= off) ? s[t - off] : 0;
    __syncthreads();
    s[t] += a;
    __syncthreads();
  }
  bsum[256 + t] = s[t] - v;
  if (t == 255) rp[n] = s[255];
}

__global__ __launch_bounds__(256) void scan_c(
    const int* __restrict__ in_deg, const int* __restrict__ out_deg,
    const int* __restrict__ bsum, int* __restrict__ rp,
    float* __restrict__ inv_src, float* __restrict__ inv_dst,
    float* __restrict__ inv_den, int n) {
  __shared__ int s[256];
  const int t = threadIdx.x;
  const int i = blockIdx.x * 256 + t;
  int v = (i < n) ? in_deg[i] : 0;
  s[t] = v;
  __syncthreads();
  #pragma unroll
  for (int off = 1; off < 256; off <<= 1) {
    int a = (t >= off) ? s[t - off] : 0;
    __syncthreads();
    s[t] += a;
    __syncthreads();
  }
  if (i < n) {
    rp[i] = bsum[256 + blockIdx.x] + s[t] - v;
    float od = (float)out_deg[i];
    float id = (float)v;
    inv_src[i] = rsqrtf(od > 0.f ? od : 1.0f);
    inv_dst[i] = rsqrtf(id > 0.f ? id : 1.0f);
    inv_den[i] = 1.0f / (id + 1.0f);
  }
}

__global__ __launch_bounds__(1024) void scatter_kernel(
    const int* __restrict__ src, const int* __restrict__ dst,
    const int* __restrict__ rp, const int* __restrict__ ord,
    const uint32_t* __restrict__ H, int* __restrict__ csr,
    int E, int bins2, int CE) {
  __shared__ uint32_t hh[25088];
  const uint32_t* Hc = H + (size_t)blockIdx.x * bins2;
  for (int i = threadIdx.x; i < bins2; i += 1024) hh[i] = Hc[i];
  __syncthreads();
  const int base = blockIdx.x * CE;
  int lim = base + CE; if (lim > E) lim = E;
  for (int e = base + (int)threadIdx.x; e < lim; e += 1024) {
    int d = dst[e];
    int b = (int)((hh[d >> 1] >> ((d & 1) * 16)) & 0xFFFFu);
    csr[rp[d] + b + ord[e]] = src[e];
  }
}

// ---------------- fp32 -> fp16 conversion ----------------

__global__ __launch_bounds__(256) void cvt_kernel(
    const float* __restrict__ in, _Float16* __restrict__ out,
    long n_in, long n_pad) {
  long i = ((long)blockIdx.x * 256 + (long)threadIdx.x) * 4;
  if (i >= n_pad) return;
  float4 v = (i < n_in) ? *(const float4*)(in + i) : make_float4(0.f, 0.f, 0.f, 0.f);
  h4 h = {(_Float16)v.x, (_Float16)v.y, (_Float16)v.z, (_Float16)v.w};
  *(h4*)(out + i) = h;
}

struct WArgs {
  const float* s[7];
  _Float16* d[7];
  int n[7];
};

__global__ __launch_bounds__(256) void wcvt_kernel(WArgs a) {
  const int w = blockIdx.y;
  long i = ((long)blockIdx.x * 256 + (long)threadIdx.x) * 4;
  if (i >= a.n[w]) return;
  float4 v = *(const float4*)(a.s[w] + i);
  h4 h = {(_Float16)v.x, (_Float16)v.y, (_Float16)v.z, (_Float16)v.w};
  *(h4*)(a.d[w] + i) = h;
}

// ---------------- async global->LDS helper ----------------

__device__ __forceinline__ void gload_lds16(const _Float16* g, _Float16* l) {
  __builtin_amdgcn_global_load_lds(
      (const __attribute__((address_space(1))) void*)g,
      (__attribute__((address_space(3))) void*)l, 16, 0, 0);
}

// ---------------- fp16 MFMA GEMM: C[M x Nc] = A[M x K] @ W^T ----------------
// R6 2-phase dbuf pipeline kept. Epilogue: optional row scale + bias; output
// node-major (pw=0) or panel-major [Nc/pw][Mstore][pw] (pw = panel width):
// off = (c/pw)*Mstore*pw + m*pw + c%pw.   (Mstore==Mpad for panel calls.)
// Fragment layouts (HW-verified): A/B lane l: idx=l&15, k=(l>>4)*8+j;
// C/D lane l: col=l&15, row=(l>>4)*4+reg.

template <typename OutT>
__global__ __launch_bounds__(256) void hgemm(
    const _Float16* __restrict__ A, const _Float16* __restrict__ W,
    OutT* __restrict__ C, int Mstore, int K, int Nc,
    const float* __restrict__ row_scale, const float* __restrict__ bias,
    int pw) {
  __shared__ _Float16 As[2][128 * 32];
  __shared__ _Float16 Bs[2][128 * 32];
  const int tid = threadIdx.x;
  const int bm = blockIdx.x * 128, bn = blockIdx.y * 128;
  const int wave = tid >> 6, lane = tid & 63;
  const int wm = (wave & 1) * 64, wn = (wave >> 1) * 64;
  const int lrow = lane & 15, lq = lane >> 4;

  const int r0 = tid >> 2;
  const int cc = (tid & 3) * 8;
  const _Float16* Ag = A + (size_t)(bm + r0) * K + cc;
  const _Float16* Wg = W + (size_t)(bn + r0) * K + cc;
  const size_t rs64 = (size_t)64 * K;
  const int l8 = tid * 8;

  f32x4 acc[4][4];
  #pragma unroll
  for (int i = 0; i < 4; ++i)
    #pragma unroll
    for (int j = 0; j < 4; ++j) acc[i][j] = (f32x4){0.f, 0.f, 0.f, 0.f};

  const int nt = K >> 5;
  gload_lds16(Ag, As[0] + l8);
  gload_lds16(Ag + rs64, As[0] + 64 * 32 + l8);
  gload_lds16(Wg, Bs[0] + l8);
  gload_lds16(Wg + rs64, Bs[0] + 64 * 32 + l8);
  __syncthreads();

  int cur = 0;
  for (int t = 0; t < nt; ++t) {
    if (t + 1 < nt) {
      const int k1 = (t + 1) << 5;
      gload_lds16(Ag + k1, As[cur ^ 1] + l8);
      gload_lds16(Ag + rs64 + k1, As[cur ^ 1] + 64 * 32 + l8);
      gload_lds16(Wg + k1, Bs[cur ^ 1] + l8);
      gload_lds16(Wg + rs64 + k1, Bs[cur ^ 1] + 64 * 32 + l8);
    }
    h8 af[4], bf[4];
    #pragma unroll
    for (int i = 0; i < 4; ++i)
      af[i] = *(const h8*)(As[cur] + (wm + i * 16 + lrow) * 32 + lq * 8);
    #pragma unroll
    for (int j = 0; j < 4; ++j)
      bf[j] = *(const h8*)(Bs[cur] + (wn + j * 16 + lrow) * 32 + lq * 8);
    #pragma unroll
    for (int i = 0; i < 4; ++i)
      #pragma unroll
      for (int j = 0; j < 4; ++j)
        acc[i][j] = __builtin_amdgcn_mfma_f32_16x16x32_f16(af[i], bf[j], acc[i][j], 0, 0, 0);
    __syncthreads();
    cur ^= 1;
  }

  #pragma unroll
  for (int i = 0; i < 4; ++i) {
    #pragma unroll
    for (int r = 0; r < 4; ++r) {
      const int m = bm + wm + i * 16 + lq * 4 + r;
      if (m < Mstore) {
        const float rsc = row_scale ? row_scale[m] : 1.0f;
        #pragma unroll
        for (int j = 0; j < 4; ++j) {
          const int c = bn + wn + j * 16 + lrow;
          float v = acc[i][j][r] * rsc;
          if (bias) v += bias[c];
          const size_t off = pw
              ? ((size_t)(c / pw) * (size_t)Mstore * pw + (size_t)m * pw + (c % pw))
              : ((size_t)m * Nc + (size_t)c);
          C[off] = (OutT)v;
        }
      }
    }
  }
}

// ---------------- panel-XCD CSR aggregation ----------------
// Z panel-major [NPAN][Mpad][W]; panel = blockIdx.x & 7 rides the HW
// round-robin block->XCD mapping so each XCD's 4 MB L2 holds one panel
// (N*W*2 B = 4.8/3.2 MB). NPAN=4 (D=128): two XCDs share a panel, REP=2
// node partitions. 8-lane groups per node, ACT=W/8 active 16B-chunk lanes.
// csr loads + out stores nontemporal (don't evict the panel). Per-column
// edge order unchanged -> output bitwise-identical to the full-D agg.
// out[node] = relu(((sum_edges Z[s]) (+Z[node] if SELF)) * scale + bias).

template <int W, int NPAN, bool SELF>
__global__ __launch_bounds__(256) void agg_p(
    const _Float16* __restrict__ Zpm, const int* __restrict__ row_ptr,
    const int* __restrict__ csr, const float* __restrict__ out_scale,
    const float* __restrict__ bias, _Float16* __restrict__ out,
    int n, int Mpad, int D, int T) {
  constexpr int ACT = W / 8;
  constexpr int REP = 8 / NPAN;
  const int pslot = blockIdx.x & 7;
  const int panel = pslot % NPAN;
  const int rep   = pslot / NPAN;
  const int tix   = (blockIdx.x >> 3) * REP + rep;
  const int ntile = T * REP;
  const int gid   = threadIdx.x >> 3;   // 32 node-groups per block
  const int l8    = threadIdx.x & 7;
  const _Float16* Zp = Zpm + (size_t)panel * ((size_t)Mpad * W);
  const int cbase = panel * W + l8 * 8;

  for (int node = tix * 32 + gid; node < n; node += ntile * 32) {
    const int rs = row_ptr[node], re = row_ptr[node + 1];
    float acc[8];
    #pragma unroll
    for (int q = 0; q < 8; ++q) acc[q] = 0.f;

    for (int e = rs; e < re; e += 8) {
      int m = re - e; if (m > 8) m = 8;
      int eid = (l8 < m) ? __builtin_nontemporal_load(csr + e + l8) : 0;
      for (int j = 0; j < m; ++j) {
        int s = __shfl(eid, j, 8);
        if (l8 < ACT) {
          h8 t = *(const h8*)(Zp + (size_t)s * W + l8 * 8);
          #pragma unroll
          for (int q = 0; q < 8; ++q) acc[q] += (float)t[q];
        }
      }
    }

    if (l8 < ACT) {
      if (SELF) {
        h8 t = *(const h8*)(Zp + (size_t)node * W + l8 * 8);
        #pragma unroll
        for (int q = 0; q < 8; ++q) acc[q] += (float)t[q];
      }
      const float osc = out_scale[node];
      h8 r;
      #pragma unroll
      for (int q = 0; q < 8; ++q) {
        float x = acc[q] * osc + bias[cbase + q];
        r[q] = (_Float16)fmaxf(x, 0.f);
      }
      __builtin_nontemporal_store(r, (h8*)(out + (size_t)node * D + cbase));
    }
  }
}

// ---------------- host-side orchestration ----------------

extern "C" void kernel_launch(void* const* d_in, const int* in_sizes, int n_in,
                              void* d_out, int out_size, void* d_ws, size_t ws_size,
                              hipStream_t stream) {
  const float* features = (const float*)d_in[0];
  const int*   src      = (const int*)d_in[1];
  const int*   dst      = (const int*)d_in[2];
  const float* wsrc[7] = {(const float*)d_in[3],  (const float*)d_in[5],
                          (const float*)d_in[7],  (const float*)d_in[9],
                          (const float*)d_in[11], (const float*)d_in[13],
                          (const float*)d_in[15]};  // sw0,gw0,sw1,gw1,sw2,gw2,fc
  const float* sb[3] = {(const float*)d_in[4],  (const float*)d_in[8],  (const float*)d_in[12]};
  const float* gb[3] = {(const float*)d_in[6],  (const float*)d_in[10], (const float*)d_in[14]};
  const float* fc_b  = (const float*)d_in[16];

  const int N = in_sizes[0] / 512;
  const int E = in_sizes[1];
  const int MB = (N + 127) / 128;
  const int Mpad = MB * 128;
  const int bins2 = (N + 1) / 2;
  if (bins2 > 25088) return;  // LDS histogram capacity

  const int wcnt[7] = {384 * 512, 384 * 384, 256 * 384, 256 * 256,
                       128 * 256, 128 * 128, 128 * 128};

  // workspace layout (fp16 buffers first, 16B-aligned throughout)
  char* ws = (char*)d_ws;
  _Float16* featH = (_Float16*)ws;                       // Mpad*512
  _Float16* hA    = featH + (size_t)Mpad * 512;          // Mpad*384 (node-major activations)
  _Float16* hB    = hA + (size_t)Mpad * 384;             // Mpad*384 (Z, panel-major)
  _Float16* wH[7];
  {
    _Float16* p = hB + (size_t)Mpad * 384;
    for (int i = 0; i < 7; ++i) { wH[i] = p; p += wcnt[i]; }
  }
  int* csr     = (int*)(wH[6] + wcnt[6]);                // E ints
  int* rp      = csr + E;                                // N+1
  int* in_dg   = rp + (N + 1);                           // N
  int* out_dg  = in_dg + N;                              // N
  int* sblk    = out_dg + N;                             // N (scan scratch, needs 512)
  float* inv_src = (float*)(sblk + N);                   // N
  float* inv_dst = inv_src + N;                          // N
  float* inv_den = inv_dst + N;                          // N

  // CSR-build scratch aliased into hA/hB (consumed before first GEMM/agg):
  int*      ord  = (int*)hB;
  uint32_t* Hsrc = (uint32_t*)(ord + E);
  uint32_t* Hdst = (uint32_t*)hA;

  size_t totw = 0; for (int i = 0; i < 7; ++i) totw += wcnt[i];
  size_t needed = ((size_t)Mpad * (512 + 384 + 384) + totw) * 2 +
                  ((size_t)E + (N + 1) + 6 * (size_t)N) * 4;
  if (ws_size < needed) return;

  const int CE = (E + NCH - 1) / NCH;
  const int nb256 = (N + 255) / 256;
  const int binsb = (bins2 + 255) / 256;

  histo_dst_kernel<<<NCH, 1024, 0, stream>>>(dst, Hdst, ord, E, bins2, CE);
  histo_out_kernel<<<HB, 1024, 0, stream>>>(src, Hsrc, E, bins2);
  chunk_scan_kernel<<<binsb, 256, 0, stream>>>(Hdst, Hsrc, in_dg, out_dg, bins2, N);
  scan_a<<<nb256, 256, 0, stream>>>(in_dg, sblk, N);
  scan_b<<<1, 256, 0, stream>>>(sblk, rp, nb256, N);
  scan_c<<<nb256, 256, 0, stream>>>(in_dg, out_dg, sblk, rp,
                                    inv_src, inv_dst, inv_den, N);
  scatter_kernel<<<NCH, 1024, 0, stream>>>(src, dst, rp, ord, Hdst, csr,
                                           E, bins2, CE);

  // conversions
  {
    long thr = (long)Mpad * 512 / 4;
    cvt_kernel<<<(int)((thr + 255) / 256), 256, 0, stream>>>(
        features, featH, (long)N * 512, (long)Mpad * 512);
    WArgs wa;
    int maxn = 0;
    for (int i = 0; i < 7; ++i) {
      wa.s[i] = wsrc[i]; wa.d[i] = wH[i]; wa.n[i] = wcnt[i];
      if (wcnt[i] > maxn) maxn = wcnt[i];
    }
    dim3 wg((maxn / 4 + 255) / 256, 7);
    wcvt_kernel<<<wg, 256, 0, stream>>>(wa);
  }

  const int dout[3] = {384, 256, 128};
  const int pwj[3]  = {48, 32, 32};   // panel widths: 8/8/4 panels
  const _Float16* h = featH;
  int K = 512;
  const int T = 192;                  // node-blocks per panel slot
  const int ag = 8 * T;               // agg grid
  for (int s = 0; s < 3; ++s) {
    const int D = dout[s];
    const int pw = pwj[s];
    dim3 gg(MB, D / 128);
    // SAGE: Z = h @ sw^T (panel-major); h' = relu((sum_in Z + Z_self)*inv_den + sb)
    hgemm<_Float16><<<gg, 256, 0, stream>>>(h, wH[2 * s], hB, Mpad, K, D,
                                            nullptr, nullptr, pw);
    if (D == 384)      agg_p<48, 8, true><<<ag, 256, 0, stream>>>(hB, rp, csr, inv_den, sb[s], hA, N, Mpad, D, T);
    else if (D == 256) agg_p<32, 8, true><<<ag, 256, 0, stream>>>(hB, rp, csr, inv_den, sb[s], hA, N, Mpad, D, T);
    else               agg_p<32, 4, true><<<ag, 256, 0, stream>>>(hB, rp, csr, inv_den, sb[s], hA, N, Mpad, D, T);
    // GraphConv: Z = (h'*inv_src) @ gw^T (panel-major); h'' = relu((sum_in Z)*inv_dst + gb)
    hgemm<_Float16><<<gg, 256, 0, stream>>>(hA, wH[2 * s + 1], hB, Mpad, D, D,
                                            inv_src, nullptr, pw);
    if (D == 384)      agg_p<48, 8, false><<<ag, 256, 0, stream>>>(hB, rp, csr, inv_dst, gb[s], hA, N, Mpad, D, T);
    else if (D == 256) agg_p<32, 8, false><<<ag, 256, 0, stream>>>(hB, rp, csr, inv_dst, gb[s], hA, N, Mpad, D, T);
    else               agg_p<32, 4, false><<<ag, 256, 0, stream>>>(hB, rp, csr, inv_dst, gb[s], hA, N, Mpad, D, T);
    h = hA;
    K = D;
  }
  // final FC: fp32 out + bias, no relu, node-major
  dim3 gf(MB, 1);
  hgemm<float><<<gf, 256, 0, stream>>>(h, wH[6], (float*)d_out, N, 128, 128,
                                       nullptr, fc_b, 0);
}

// Round 8
// 1161.927 us; speedup vs baseline: 1.4222x; 1.4222x over previous
//
#include <hip/hip_runtime.h>
#include <cstddef>
#include <cstdint>

// ---------------------------------------------------------------------------
// N=50000 nodes, E=1,650,000 edges (incl. self loops). Stages (in,out):
// (512,384),(384,256),(256,128), FC 128->128.
// Pipeline (all activations/weights fp16, accumulation fp32):
//   convert -> [per stage: MFMA GEMM -> CSR agg] x6 -> MFMA FC (fp32 out)
// GEMM-first restructuring: (A h) W^T == A (h W^T); row scales commute.
// R8: agg reverted to R6 agg_h (R7 panel: FETCH -41% proved XCD-L2 residency
//     works, but 96B-row straddle + VGPR-20 serialization lost 34%; aligned
//     W<=41 is geometrically impossible -> parked).
//     GEMM grid XCD-grouped: 1-D grid, xcd=bid&7 owns bm-groups g==xcd (mod 8)
//     with the NT=D/128 N-tile peers adjacent on that XCD -> each XCD stages
//     only its 1/8 A-slice once (MSHR-merged), vs ~all of A per XCD under
//     default round-robin. Cuts A L3 traffic ~8-24x per GEMM. Bit-identical C.
// ---------------------------------------------------------------------------

typedef _Float16 h8 __attribute__((ext_vector_type(8)));
typedef _Float16 h4 __attribute__((ext_vector_type(4)));
typedef float f32x4 __attribute__((ext_vector_type(4)));

#define HB 64    // src-histogram blocks
#define NCH 256  // dst chunks (per-chunk count <= E/256 = 6446 < 65536)

// ---------------- degree / CSR build (no global atomics) ----------------

__global__ __launch_bounds__(1024) void histo_dst_kernel(
    const int* __restrict__ dst, uint32_t* __restrict__ H,
    int* __restrict__ ord, int E, int bins2, int CE) {
  __shared__ uint32_t hh[25088];  // 100 KB, 2 x u16 bins per u32
  for (int i = threadIdx.x; i < bins2; i += 1024) hh[i] = 0;
  __syncthreads();
  const int base = blockIdx.x * CE;
  int lim = base + CE; if (lim > E) lim = E;
  for (int e = base + (int)threadIdx.x; e < lim; e += 1024) {
    int d = dst[e];
    const int sh = (d & 1) * 16;
    uint32_t old = atomicAdd(&hh[d >> 1], 1u << sh);
    ord[e] = (int)((old >> sh) & 0xFFFFu);
  }
  __syncthreads();
  uint32_t* out = H + (size_t)blockIdx.x * bins2;
  for (int i = threadIdx.x; i < bins2; i += 1024) out[i] = hh[i];
}

__global__ __launch_bounds__(1024) void histo_out_kernel(
    const int* __restrict__ src, uint32_t* __restrict__ H, int E, int bins2) {
  __shared__ uint32_t hh[25088];
  for (int i = threadIdx.x; i < bins2; i += 1024) hh[i] = 0;
  __syncthreads();
  const int C = (E + HB - 1) / HB;
  const int base = blockIdx.x * C;
  int lim = base + C; if (lim > E) lim = E;
  for (int e = base + (int)threadIdx.x; e < lim; e += 1024) {
    int s = src[e];
    atomicAdd(&hh[s >> 1], 1u << ((s & 1) * 16));
  }
  __syncthreads();
  uint32_t* out = H + (size_t)blockIdx.x * bins2;
  for (int i = threadIdx.x; i < bins2; i += 1024) out[i] = hh[i];
}

// exclusive scan of Hdst along chunks (packed u16) -> bases + in-degree;
// fused sum of Hsrc -> out-degree.
__global__ __launch_bounds__(256) void chunk_scan_kernel(
    uint32_t* __restrict__ Hd, const uint32_t* __restrict__ Hs,
    int* __restrict__ in_deg, int* __restrict__ out_deg, int bins2, int n) {
  int i = blockIdx.x * 256 + threadIdx.x;
  if (i >= bins2) return;
  uint32_t lo = 0, hi = 0;
  for (int c = 0; c < NCH; ++c) {
    uint32_t* p = Hd + (size_t)c * bins2 + i;
    uint32_t v = *p;
    *p = lo | (hi << 16);
    lo += v & 0xFFFFu;
    hi += v >> 16;
  }
  in_deg[2 * i] = (int)lo;
  if (2 * i + 1 < n) in_deg[2 * i + 1] = (int)hi;
  uint32_t slo = 0, shi = 0;
  for (int b = 0; b < HB; ++b) {
    uint32_t v = Hs[(size_t)b * bins2 + i];
    slo += v & 0xFFFFu;
    shi += v >> 16;
  }
  out_deg[2 * i] = (int)slo;
  if (2 * i + 1 < n) out_deg[2 * i + 1] = (int)shi;
}

// ---- 3-phase scan of in_deg -> row_ptr (nb <= 256 blocks of 256) ----

__global__ __launch_bounds__(256) void scan_a(
    const int* __restrict__ deg, int* __restrict__ bsum, int n) {
  __shared__ int s[256];
  int i = blockIdx.x * 256 + threadIdx.x;
  s[threadIdx.x] = (i < n) ? deg[i] : 0;
  __syncthreads();
  #pragma unroll
  for (int off = 128; off > 0; off >>= 1) {
    if ((int)threadIdx.x < off) s[threadIdx.x] += s[threadIdx.x + off];
    __syncthreads();
  }
  if (threadIdx.x == 0) bsum[blockIdx.x] = s[0];
}

__global__ __launch_bounds__(256) void scan_b(
    int* __restrict__ bsum, int* __restrict__ rp, int nb, int n) {
  __shared__ int s[256];
  const int t = threadIdx.x;
  int v = (t < nb) ? bsum[t] : 0;
  s[t] = v;
  __syncthreads();
  #pragma unroll
  for (int off = 1; off < 256; off <<= 1) {
    int a = (t >= off) ? s[t - off] : 0;
    __syncthreads();
    s[t] += a;
    __syncthreads();
  }
  bsum[256 + t] = s[t] - v;
  if (t == 255) rp[n] = s[255];
}

__global__ __launch_bounds__(256) void scan_c(
    const int* __restrict__ in_deg, const int* __restrict__ out_deg,
    const int* __restrict__ bsum, int* __restrict__ rp,
    float* __restrict__ inv_src, float* __restrict__ inv_dst,
    float* __restrict__ inv_den, int n) {
  __shared__ int s[256];
  const int t = threadIdx.x;
  const int i = blockIdx.x * 256 + t;
  int v = (i < n) ? in_deg[i] : 0;
  s[t] = v;
  __syncthreads();
  #pragma unroll
  for (int off = 1; off < 256; off <<= 1) {
    int a = (t >= off) ? s[t - off] : 0;
    __syncthreads();
    s[t] += a;
    __syncthreads();
  }
  if (i < n) {
    rp[i] = bsum[256 + blockIdx.x] + s[t] - v;
    float od = (float)out_deg[i];
    float id = (float)v;
    inv_src[i] = rsqrtf(od > 0.f ? od : 1.0f);
    inv_dst[i] = rsqrtf(id > 0.f ? id : 1.0f);
    inv_den[i] = 1.0f / (id + 1.0f);
  }
}

__global__ __launch_bounds__(1024) void scatter_kernel(
    const int* __restrict__ src, const int* __restrict__ dst,
    const int* __restrict__ rp, const int* __restrict__ ord,
    const uint32_t* __restrict__ H, int* __restrict__ csr,
    int E, int bins2, int CE) {
  __shared__ uint32_t hh[25088];
  const uint32_t* Hc = H + (size_t)blockIdx.x * bins2;
  for (int i = threadIdx.x; i < bins2; i += 1024) hh[i] = Hc[i];
  __syncthreads();
  const int base = blockIdx.x * CE;
  int lim = base + CE; if (lim > E) lim = E;
  for (int e = base + (int)threadIdx.x; e < lim; e += 1024) {
    int d = dst[e];
    int b = (int)((hh[d >> 1] >> ((d & 1) * 16)) & 0xFFFFu);
    csr[rp[d] + b + ord[e]] = src[e];
  }
}

// ---------------- fp32 -> fp16 conversion ----------------

__global__ __launch_bounds__(256) void cvt_kernel(
    const float* __restrict__ in, _Float16* __restrict__ out,
    long n_in, long n_pad) {
  long i = ((long)blockIdx.x * 256 + (long)threadIdx.x) * 4;
  if (i >= n_pad) return;
  float4 v = (i < n_in) ? *(const float4*)(in + i) : make_float4(0.f, 0.f, 0.f, 0.f);
  h4 h = {(_Float16)v.x, (_Float16)v.y, (_Float16)v.z, (_Float16)v.w};
  *(h4*)(out + i) = h;
}

struct WArgs {
  const float* s[7];
  _Float16* d[7];
  int n[7];
};

__global__ __launch_bounds__(256) void wcvt_kernel(WArgs a) {
  const int w = blockIdx.y;
  long i = ((long)blockIdx.x * 256 + (long)threadIdx.x) * 4;
  if (i >= a.n[w]) return;
  float4 v = *(const float4*)(a.s[w] + i);
  h4 h = {(_Float16)v.x, (_Float16)v.y, (_Float16)v.z, (_Float16)v.w};
  *(h4*)(a.d[w] + i) = h;
}

// ---------------- async global->LDS helper ----------------

__device__ __forceinline__ void gload_lds16(const _Float16* g, _Float16* l) {
  __builtin_amdgcn_global_load_lds(
      (const __attribute__((address_space(1))) void*)g,
      (__attribute__((address_space(3))) void*)l, 16, 0, 0);
}

// ---------------- fp16 MFMA GEMM: C[M x Nc] = A[M x K] @ W^T ----------------
// R6 2-phase dbuf pipeline. R8: 1-D XCD-grouped grid. Block decode:
//   xcd = bid&7, s = bid>>3, bm-group = xcd + 8*(s/NT), bn = s%NT.
// XCD x's dispatch sequence walks (g, bn=0..NT-1) with the NT peers adjacent
// -> each XCD stages only bm-rows g==x (mod 8) (1/8 of A), and the NT re-reads
// hit its L2 / merge in MSHRs. grid = 8*ceil(MBp/8)*NT; bm>=MBp blocks exit.
// Fragment layouts (HW-verified): A/B lane l: idx=l&15, k=(l>>4)*8+j;
// C/D lane l: col=l&15, row=(l>>4)*4+reg.

template <typename OutT>
__global__ __launch_bounds__(256) void hgemm(
    const _Float16* __restrict__ A, const _Float16* __restrict__ W,
    OutT* __restrict__ C, int Mstore, int K, int Nc,
    const float* __restrict__ row_scale, const float* __restrict__ bias,
    int MBp, int NT) {
  const int xcd = blockIdx.x & 7;
  const int sl  = blockIdx.x >> 3;
  const int bmi = xcd + 8 * (sl / NT);
  if (bmi >= MBp) return;
  const int bm = bmi * 128;
  const int bn = (sl % NT) * 128;

  __shared__ _Float16 As[2][128 * 32];
  __shared__ _Float16 Bs[2][128 * 32];
  const int tid = threadIdx.x;
  const int wave = tid >> 6, lane = tid & 63;
  const int wm = (wave & 1) * 64, wn = (wave >> 1) * 64;
  const int lrow = lane & 15, lq = lane >> 4;

  const int r0 = tid >> 2;
  const int cc = (tid & 3) * 8;
  const _Float16* Ag = A + (size_t)(bm + r0) * K + cc;
  const _Float16* Wg = W + (size_t)(bn + r0) * K + cc;
  const size_t rs64 = (size_t)64 * K;
  const int l8 = tid * 8;

  f32x4 acc[4][4];
  #pragma unroll
  for (int i = 0; i < 4; ++i)
    #pragma unroll
    for (int j = 0; j < 4; ++j) acc[i][j] = (f32x4){0.f, 0.f, 0.f, 0.f};

  const int nt = K >> 5;
  gload_lds16(Ag, As[0] + l8);
  gload_lds16(Ag + rs64, As[0] + 64 * 32 + l8);
  gload_lds16(Wg, Bs[0] + l8);
  gload_lds16(Wg + rs64, Bs[0] + 64 * 32 + l8);
  __syncthreads();

  int cur = 0;
  for (int t = 0; t < nt; ++t) {
    if (t + 1 < nt) {
      const int k1 = (t + 1) << 5;
      gload_lds16(Ag + k1, As[cur ^ 1] + l8);
      gload_lds16(Ag + rs64 + k1, As[cur ^ 1] + 64 * 32 + l8);
      gload_lds16(Wg + k1, Bs[cur ^ 1] + l8);
      gload_lds16(Wg + rs64 + k1, Bs[cur ^ 1] + 64 * 32 + l8);
    }
    h8 af[4], bf[4];
    #pragma unroll
    for (int i = 0; i < 4; ++i)
      af[i] = *(const h8*)(As[cur] + (wm + i * 16 + lrow) * 32 + lq * 8);
    #pragma unroll
    for (int j = 0; j < 4; ++j)
      bf[j] = *(const h8*)(Bs[cur] + (wn + j * 16 + lrow) * 32 + lq * 8);
    #pragma unroll
    for (int i = 0; i < 4; ++i)
      #pragma unroll
      for (int j = 0; j < 4; ++j)
        acc[i][j] = __builtin_amdgcn_mfma_f32_16x16x32_f16(af[i], bf[j], acc[i][j], 0, 0, 0);
    __syncthreads();
    cur ^= 1;
  }

  #pragma unroll
  for (int i = 0; i < 4; ++i) {
    #pragma unroll
    for (int r = 0; r < 4; ++r) {
      const int m = bm + wm + i * 16 + lq * 4 + r;
      if (m < Mstore) {
        const float rsc = row_scale ? row_scale[m] : 1.0f;
        OutT* crow = C + (size_t)m * Nc + bn + wn + lrow;
        #pragma unroll
        for (int j = 0; j < 4; ++j) {
          float v = acc[i][j][r] * rsc;
          if (bias) v += bias[bn + wn + j * 16 + lrow];
          crow[j * 16] = (OutT)v;
        }
      }
    }
  }
}

// ---------------- CSR aggregation, fp16 gather / fp32 accumulate ----------------
// out[n] = relu(((sum_{e:dst=n} Z[csr[e]]) (+ Z[n] if SELF)) * out_scale[n] + bias)
// 16 lanes per node; 16B gathers. R6 form (known-good 180/118/59 us). Evidence
// R1-R7: memory-request-path bound (6 lines/edge, ~55% L2 hit); ILP/occupancy/
// panel variants all null or worse at fp16.

template <int D, bool SELF>
__global__ __launch_bounds__(256) void agg_h(
    const _Float16* __restrict__ Z, const int* __restrict__ row_ptr,
    const int* __restrict__ csr, const float* __restrict__ out_scale,
    const float* __restrict__ bias, _Float16* __restrict__ out, int n) {
  constexpr int CH = D / 8;       // 16B chunks per row (48/32/16)
  constexpr int GROUP = 16;
  constexpr int NV = CH / GROUP;  // 3/2/1 chunks per lane
  const int gid = threadIdx.x >> 4;
  const int lane = threadIdx.x & 15;
  const int stride = gridDim.x * 16;

  for (int node = blockIdx.x * 16 + gid; node < n; node += stride) {
    const int rs = row_ptr[node], re = row_ptr[node + 1];

    float acc[NV][8];
    #pragma unroll
    for (int v = 0; v < NV; ++v)
      #pragma unroll
      for (int q = 0; q < 8; ++q) acc[v][q] = 0.f;

    for (int e = rs; e < re; e += GROUP) {
      int m = re - e; if (m > GROUP) m = GROUP;
      int eid = (lane < m) ? csr[e + lane] : 0;
      for (int j = 0; j < m; ++j) {
        int s = __shfl(eid, j, GROUP);
        const h8* zr = (const h8*)(Z + (size_t)s * D);
        #pragma unroll
        for (int v = 0; v < NV; ++v) {
          h8 t = zr[lane + v * GROUP];
          #pragma unroll
          for (int q = 0; q < 8; ++q) acc[v][q] += (float)t[q];
        }
      }
    }

    const float osc = out_scale[node];
    const h8* zs = (const h8*)(Z + (size_t)node * D);
    _Float16* orow = out + (size_t)node * D;
    #pragma unroll
    for (int v = 0; v < NV; ++v) {
      const int idx = lane + v * GROUP;
      if (SELF) {
        h8 t = zs[idx];
        #pragma unroll
        for (int q = 0; q < 8; ++q) acc[v][q] += (float)t[q];
      }
      h8 r;
      #pragma unroll
      for (int q = 0; q < 8; ++q) {
        float x = acc[v][q] * osc + bias[idx * 8 + q];
        r[q] = (_Float16)fmaxf(x, 0.f);
      }
      *(h8*)(orow + idx * 8) = r;
    }
  }
}

// ---------------- host-side orchestration ----------------

extern "C" void kernel_launch(void* const* d_in, const int* in_sizes, int n_in,
                              void* d_out, int out_size, void* d_ws, size_t ws_size,
                              hipStream_t stream) {
  const float* features = (const float*)d_in[0];
  const int*   src      = (const int*)d_in[1];
  const int*   dst      = (const int*)d_in[2];
  const float* wsrc[7] = {(const float*)d_in[3],  (const float*)d_in[5],
                          (const float*)d_in[7],  (const float*)d_in[9],
                          (const float*)d_in[11], (const float*)d_in[13],
                          (const float*)d_in[15]};  // sw0,gw0,sw1,gw1,sw2,gw2,fc
  const float* sb[3] = {(const float*)d_in[4],  (const float*)d_in[8],  (const float*)d_in[12]};
  const float* gb[3] = {(const float*)d_in[6],  (const float*)d_in[10], (const float*)d_in[14]};
  const float* fc_b  = (const float*)d_in[16];

  const int N = in_sizes[0] / 512;
  const int E = in_sizes[1];
  const int MB = (N + 127) / 128;
  const int Mpad = MB * 128;
  const int bins2 = (N + 1) / 2;
  if (bins2 > 25088) return;  // LDS histogram capacity

  const int wcnt[7] = {384 * 512, 384 * 384, 256 * 384, 256 * 256,
                       128 * 256, 128 * 128, 128 * 128};

  // workspace layout (fp16 buffers first, 16B-aligned throughout)
  char* ws = (char*)d_ws;
  _Float16* featH = (_Float16*)ws;                       // Mpad*512
  _Float16* hA    = featH + (size_t)Mpad * 512;          // Mpad*384 (activations)
  _Float16* hB    = hA + (size_t)Mpad * 384;             // Mpad*384 (Z)
  _Float16* wH[7];
  {
    _Float16* p = hB + (size_t)Mpad * 384;
    for (int i = 0; i < 7; ++i) { wH[i] = p; p += wcnt[i]; }
  }
  int* csr     = (int*)(wH[6] + wcnt[6]);                // E ints
  int* rp      = csr + E;                                // N+1
  int* in_dg   = rp + (N + 1);                           // N
  int* out_dg  = in_dg + N;                              // N
  int* sblk    = out_dg + N;                             // N (scan scratch, needs 512)
  float* inv_src = (float*)(sblk + N);                   // N
  float* inv_dst = inv_src + N;                          // N
  float* inv_den = inv_dst + N;                          // N

  // CSR-build scratch aliased into hA/hB (consumed before first GEMM/agg):
  int*      ord  = (int*)hB;
  uint32_t* Hsrc = (uint32_t*)(ord + E);
  uint32_t* Hdst = (uint32_t*)hA;

  size_t totw = 0; for (int i = 0; i < 7; ++i) totw += wcnt[i];
  size_t needed = ((size_t)Mpad * (512 + 384 + 384) + totw) * 2 +
                  ((size_t)E + (N + 1) + 6 * (size_t)N) * 4;
  if (ws_size < needed) return;

  const int CE = (E + NCH - 1) / NCH;
  const int nb256 = (N + 255) / 256;
  const int binsb = (bins2 + 255) / 256;

  histo_dst_kernel<<<NCH, 1024, 0, stream>>>(dst, Hdst, ord, E, bins2, CE);
  histo_out_kernel<<<HB, 1024, 0, stream>>>(src, Hsrc, E, bins2);
  chunk_scan_kernel<<<binsb, 256, 0, stream>>>(Hdst, Hsrc, in_dg, out_dg, bins2, N);
  scan_a<<<nb256, 256, 0, stream>>>(in_dg, sblk, N);
  scan_b<<<1, 256, 0, stream>>>(sblk, rp, nb256, N);
  scan_c<<<nb256, 256, 0, stream>>>(in_dg, out_dg, sblk, rp,
                                    inv_src, inv_dst, inv_den, N);
  scatter_kernel<<<NCH, 1024, 0, stream>>>(src, dst, rp, ord, Hdst, csr,
                                           E, bins2, CE);

  // conversions
  {
    long thr = (long)Mpad * 512 / 4;
    cvt_kernel<<<(int)((thr + 255) / 256), 256, 0, stream>>>(
        features, featH, (long)N * 512, (long)Mpad * 512);
    WArgs wa;
    int maxn = 0;
    for (int i = 0; i < 7; ++i) {
      wa.s[i] = wsrc[i]; wa.d[i] = wH[i]; wa.n[i] = wcnt[i];
      if (wcnt[i] > maxn) maxn = wcnt[i];
    }
    dim3 wg((maxn / 4 + 255) / 256, 7);
    wcvt_kernel<<<wg, 256, 0, stream>>>(wa);
  }

  const int MB8 = (MB + 7) / 8;        // bm-groups per XCD
  const int dout[3] = {384, 256, 128};
  const _Float16* h = featH;
  int K = 512;
  const int ab = (N + 31) / 32;        // agg: 2 node-tiles per block
  for (int s = 0; s < 3; ++s) {
    const int D = dout[s];
    const int NT = D / 128;
    const int gx = 8 * MB8 * NT;       // XCD-grouped 1-D GEMM grid
    // SAGE: Z = h @ sw^T ; h' = relu((sum_in Z + Z_self)*inv_den + sb)
    hgemm<_Float16><<<gx, 256, 0, stream>>>(h, wH[2 * s], hB, Mpad, K, D,
                                            nullptr, nullptr, MB, NT);
    if (D == 384)      agg_h<384, true><<<ab, 256, 0, stream>>>(hB, rp, csr, inv_den, sb[s], hA, N);
    else if (D == 256) agg_h<256, true><<<ab, 256, 0, stream>>>(hB, rp, csr, inv_den, sb[s], hA, N);
    else               agg_h<128, true><<<ab, 256, 0, stream>>>(hB, rp, csr, inv_den, sb[s], hA, N);
    // GraphConv: Z = (h'*inv_src) @ gw^T ; h'' = relu((sum_in Z)*inv_dst + gb)
    hgemm<_Float16><<<gx, 256, 0, stream>>>(hA, wH[2 * s + 1], hB, Mpad, D, D,
                                            inv_src, nullptr, MB, NT);
    if (D == 384)      agg_h<384, false><<<ab, 256, 0, stream>>>(hB, rp, csr, inv_dst, gb[s], hA, N);
    else if (D == 256) agg_h<256, false><<<ab, 256, 0, stream>>>(hB, rp, csr, inv_dst, gb[s], hA, N);
    else               agg_h<128, false><<<ab, 256, 0, stream>>>(hB, rp, csr, inv_dst, gb[s], hA, N);
    h = hA;
    K = D;
  }
  // final FC: fp32 out + bias, no relu
  hgemm<float><<<8 * MB8, 256, 0, stream>>>(h, wH[6], (float*)d_out, N, 128, 128,
                                            nullptr, fc_b, MB, 1);
}